// Round 1
// baseline (724.887 us; speedup 1.0000x reference)
//
#include <hip/hip_runtime.h>
#include <cstddef>

#define NB 256        // batch
#define CH 256        // channels
#define NTOK 320      // 256 value tokens + 64 query tokens
#define NPW 320       // pw columns
#define NCOL 323      // NP + K
#define RT 8          // rows per block, kernel 1
#define MT 8          // output rows per block, kernel 2
#define LN_EPS 1e-5f

// Kernel 1: dy = x @ w_lin + b_lin (per-token row of 323 cols),
// store pw = dy[:, :, 3:] for token rows < 256, then depthwise
// 3-tap conv over channels with dw = dy[:, :, 0:3], ReLU, store r.
__global__ __launch_bounds__(320) void dy_conv_kernel(
    const float* __restrict__ query, const float* __restrict__ value,
    const float* __restrict__ w, const float* __restrict__ bl,
    float* __restrict__ pw, float* __restrict__ r)
{
    __shared__ float xs[RT][CH + 2];   // zero halo at [0] and [CH+1]
    __shared__ float dwv[RT][4];
    const int t   = threadIdx.x;       // 0..319 : dy column index
    const int blk = blockIdx.x;
    const int b   = blk / (NTOK / RT);
    const int n0  = (blk % (NTOK / RT)) * RT;

    // stage 8 token rows of x into LDS (coalesced)
    if (t < CH) {
        #pragma unroll
        for (int i = 0; i < RT; ++i) {
            const int n = n0 + i;
            const float xv = (n < 256)
                ? value[((size_t)b * 256 + n) * CH + t]
                : query[((size_t)b * 64 + (n - 256)) * CH + t];
            xs[i][1 + t] = xv;
        }
    }
    if (t < RT) { xs[t][0] = 0.0f; xs[t][CH + 1] = 0.0f; }
    __syncthreads();

    const bool need_pw = (n0 < 256);   // query rows only need dw (cols 0..2)
    float acc[RT];
    #pragma unroll
    for (int i = 0; i < RT; ++i) acc[i] = bl[t];

    if (need_pw) {
        #pragma unroll 4
        for (int c = 0; c < CH; ++c) {
            const float w0 = w[c * NCOL + t];          // coalesced across t
            #pragma unroll
            for (int i = 0; i < RT; ++i)
                acc[i] = fmaf(xs[i][1 + c], w0, acc[i]);   // LDS broadcast
        }
        // tail columns 320..322 handled by threads 0..2
        float acc2[RT];
        if (t < 3) {
            #pragma unroll
            for (int i = 0; i < RT; ++i) acc2[i] = bl[320 + t];
            for (int c = 0; c < CH; ++c) {
                const float w1 = w[c * NCOL + 320 + t];
                #pragma unroll
                for (int i = 0; i < RT; ++i)
                    acc2[i] = fmaf(xs[i][1 + c], w1, acc2[i]);
            }
        }
        // store pw: dy col t -> pw col t-3 (t>=3); dy col 320+t -> pw col 317+t (t<3)
        #pragma unroll
        for (int i = 0; i < RT; ++i) {
            const int n = n0 + i;                      // < 256 here
            if (t >= 3) pw[((size_t)b * 256 + n) * NPW + (t - 3)]   = acc[i];
            else        pw[((size_t)b * 256 + n) * NPW + (317 + t)] = acc2[i];
        }
        if (t < 3) {
            #pragma unroll
            for (int i = 0; i < RT; ++i) dwv[i][t] = acc[i];
        }
    } else {
        if (t < 3) {
            for (int c = 0; c < CH; ++c) {
                const float w0 = w[c * NCOL + t];
                #pragma unroll
                for (int i = 0; i < RT; ++i)
                    acc[i] = fmaf(xs[i][1 + c], w0, acc[i]);
            }
            #pragma unroll
            for (int i = 0; i < RT; ++i) dwv[i][t] = acc[i];
        }
    }
    __syncthreads();

    // depthwise conv (3-tap over channel dim, zero-padded) + ReLU -> r
    if (t < CH) {
        #pragma unroll
        for (int i = 0; i < RT; ++i) {
            const int n = n0 + i;
            float v2 = dwv[i][0] * xs[i][t]
                     + dwv[i][1] * xs[i][t + 1]
                     + dwv[i][2] * xs[i][t + 2];
            v2 = fmaxf(v2, 0.0f);
            r[((size_t)b * NTOK + n) * CH + t] = v2;
        }
    }
}

// Kernel 2: out[b,m,:] = LN( sum_n pw[b,m,n] * r[b,n,:] ) * gamma + beta
__global__ __launch_bounds__(256) void pv_ln_kernel(
    const float* __restrict__ pw, const float* __restrict__ r,
    const float* __restrict__ gamma, const float* __restrict__ beta,
    float* __restrict__ out)
{
    __shared__ float ps[MT][NPW];     // 10 KB
    __shared__ float rsum[MT][4];
    __shared__ float rsq[MT][4];
    const int t  = threadIdx.x;       // channel index
    const int b  = blockIdx.x / (256 / MT);
    const int m0 = (blockIdx.x % (256 / MT)) * MT;

    for (int idx = t; idx < MT * NPW; idx += 256) {
        const int row = idx / NPW;
        const int col = idx - row * NPW;
        ps[row][col] = pw[((size_t)b * 256 + m0 + row) * NPW + col];
    }
    __syncthreads();

    float acc[MT];
    #pragma unroll
    for (int i = 0; i < MT; ++i) acc[i] = 0.0f;

    #pragma unroll 4
    for (int n = 0; n < NTOK; ++n) {
        const float rv = r[((size_t)b * NTOK + n) * CH + t];  // coalesced
        #pragma unroll
        for (int i = 0; i < MT; ++i)
            acc[i] = fmaf(ps[i][n], rv, acc[i]);              // LDS broadcast
    }

    // fused LayerNorm over the 256 channels (threads)
    const int wave = t >> 6, lane = t & 63;
    #pragma unroll
    for (int i = 0; i < MT; ++i) {
        float s = acc[i], s2 = acc[i] * acc[i];
        #pragma unroll
        for (int off = 32; off > 0; off >>= 1) {
            s  += __shfl_xor(s, off);
            s2 += __shfl_xor(s2, off);
        }
        if (lane == 0) { rsum[i][wave] = s; rsq[i][wave] = s2; }
    }
    __syncthreads();

    const float g = gamma[t], be = beta[t];
    #pragma unroll
    for (int i = 0; i < MT; ++i) {
        const float S  = rsum[i][0] + rsum[i][1] + rsum[i][2] + rsum[i][3];
        const float S2 = rsq[i][0]  + rsq[i][1]  + rsq[i][2]  + rsq[i][3];
        const float mu   = S * (1.0f / CH);
        const float var  = S2 * (1.0f / CH) - mu * mu;
        const float rstd = rsqrtf(var + LN_EPS);
        out[((size_t)b * 256 + m0 + i) * CH + t] = (acc[i] - mu) * rstd * g + be;
    }
}

extern "C" void kernel_launch(void* const* d_in, const int* in_sizes, int n_in,
                              void* d_out, int out_size, void* d_ws, size_t ws_size,
                              hipStream_t stream) {
    const float* query = (const float*)d_in[0];
    const float* value = (const float*)d_in[1];
    const float* w     = (const float*)d_in[2];
    const float* bl    = (const float*)d_in[3];
    const float* gamma = (const float*)d_in[4];
    const float* beta  = (const float*)d_in[5];
    float* out = (float*)d_out;

    float* pw = (float*)d_ws;                          // 256*256*320 floats = 83.9 MB
    float* rr = pw + (size_t)NB * 256 * NPW;           // 256*320*256 floats = 83.9 MB

    hipLaunchKernelGGL(dy_conv_kernel, dim3(NB * (NTOK / RT)), dim3(320), 0, stream,
                       query, value, w, bl, pw, rr);
    hipLaunchKernelGGL(pv_ln_kernel, dim3(NB * (256 / MT)), dim3(256), 0, stream,
                       pw, rr, gamma, beta, out);
}

// Round 2
// 155.236 us; speedup vs baseline: 4.6696x; 4.6696x over previous
//
#include <hip/hip_runtime.h>
#include <cstddef>
#include <cstdint>

#define NB 256
#define CH 256
#define NTOK 320
#define NPW 320
#define NCOL 323
#define LN_EPS 1e-5f

typedef short short8 __attribute__((ext_vector_type(8)));
typedef float floatx4 __attribute__((ext_vector_type(4)));

__device__ __forceinline__ uint16_t f2bf(float f) {
  uint32_t u = __builtin_bit_cast(uint32_t, f);
  u += 0x7FFFu + ((u >> 16) & 1u);          // round-to-nearest-even
  return (uint16_t)(u >> 16);
}

__device__ __forceinline__ void gload_lds16(const void* g, void* l) {
  __builtin_amdgcn_global_load_lds(
      (const __attribute__((address_space(1))) unsigned int*)g,
      (__attribute__((address_space(3))) unsigned int*)l, 16, 0, 0);
}

// ---------------- K00: w3t[n][k] = bf16(w[k][3+n]) ----------------
__global__ __launch_bounds__(256) void wprep_kernel(
    const float* __restrict__ w, uint16_t* __restrict__ w3t) {
  const int n = blockIdx.x;     // 0..319
  const int k = threadIdx.x;    // 0..255
  w3t[n * 256 + k] = f2bf(w[k * NCOL + 3 + n]);
}

// ---------------- K0: dw + conv -> rT (bf16, transposed), vb = bf16(value) ----
__global__ __launch_bounds__(256) void prep_kernel(
    const float* __restrict__ query, const float* __restrict__ value,
    const float* __restrict__ w, const float* __restrict__ bl,
    uint16_t* __restrict__ vb, uint16_t* __restrict__ rT)
{
  __shared__ float xs[32][256];     // 32 KB
  __shared__ float w3s[256][3];
  __shared__ float dwv[32][3];
  const int t  = threadIdx.x;
  const int b  = blockIdx.x / 10;
  const int n0 = (blockIdx.x % 10) * 32;
  const bool isval = (n0 < 256);
  const float* src = isval ? (value + ((size_t)b * 256 + n0) * CH)
                           : (query + ((size_t)b * 64 + (n0 - 256)) * CH);
  // stage 32 rows (32 KB), optionally emit vb (bf16 copy of value rows)
  #pragma unroll
  for (int q = 0; q < 8; ++q) {
    const int fe = q * 1024 + t * 4;
    const float4 v = *(const float4*)(src + fe);
    *(float4*)&xs[fe >> 8][fe & 255] = v;
    if (isval) {
      ushort4 h;
      h.x = f2bf(v.x); h.y = f2bf(v.y); h.z = f2bf(v.z); h.w = f2bf(v.w);
      *(ushort4*)(vb + ((size_t)b * 256 + n0) * CH + fe) = h;
    }
  }
  w3s[t][0] = w[t * NCOL + 0];
  w3s[t][1] = w[t * NCOL + 1];
  w3s[t][2] = w[t * NCOL + 2];
  __syncthreads();

  // dw: wave wid handles rows wid*8 .. wid*8+7
  const int wid = t >> 6, lane = t & 63;
  for (int i = 0; i < 8; ++i) {
    const int row = wid * 8 + i;
    float p0 = 0.f, p1 = 0.f, p2 = 0.f;
    #pragma unroll
    for (int q = 0; q < 4; ++q) {
      const int c = lane + q * 64;
      const float xv = xs[row][c];
      p0 = fmaf(xv, w3s[c][0], p0);
      p1 = fmaf(xv, w3s[c][1], p1);
      p2 = fmaf(xv, w3s[c][2], p2);
    }
    #pragma unroll
    for (int off = 32; off; off >>= 1) {
      p0 += __shfl_xor(p0, off);
      p1 += __shfl_xor(p1, off);
      p2 += __shfl_xor(p2, off);
    }
    if (lane == 0) {
      dwv[row][0] = p0 + bl[0];
      dwv[row][1] = p1 + bl[1];
      dwv[row][2] = p2 + bl[2];
    }
  }
  __syncthreads();

  // conv(3-tap over channels, zero pad) + ReLU, buffered -> coalesced rT rows
  uint32_t rb[16];
  #pragma unroll
  for (int i = 0; i < 32; ++i) {
    const float xm = (t > 0)   ? xs[i][t - 1] : 0.0f;
    const float xc = xs[i][t];
    const float xp = (t < 255) ? xs[i][t + 1] : 0.0f;
    float v = dwv[i][0] * xm + dwv[i][1] * xc + dwv[i][2] * xp;
    v = fmaxf(v, 0.0f);
    const uint16_t h = f2bf(v);
    if (i & 1) rb[i >> 1] |= ((uint32_t)h) << 16;
    else       rb[i >> 1]  = h;
  }
  uint4* dst = (uint4*)(rT + ((size_t)b * 256 + t) * NPW + n0);
  #pragma unroll
  for (int q = 0; q < 4; ++q) dst[q] = ((uint4*)rb)[q];
}

// ---------------- K1: pw = vb @ w3t^T + bias  (MFMA bf16) ----------------
// per batch: M=256 (value tokens), N=320 (pw cols), K=256. BM=128, BN=160, BK=32.
__global__ __launch_bounds__(256) void gemm1_kernel(
    const uint16_t* __restrict__ vb, const uint16_t* __restrict__ w3t,
    const float* __restrict__ bl, uint16_t* __restrict__ pw)
{
  __shared__ uint16_t as_[128 * 32];   // 8 KB, [m][k] row-major
  __shared__ uint16_t bs_[160 * 32];   // 10 KB, [n][k] row-major
  const int t   = threadIdx.x;
  const int bid = blockIdx.x;
  const int b   = bid >> 2;
  const int m0  = ((bid >> 1) & 1) * 128;
  const int n0  = (bid & 1) * 160;
  const int wid = t >> 6, lane = t & 63;
  const int wm = wid >> 1, wn = wid & 1;
  const int lr = lane & 15, lg = lane >> 4;

  const uint16_t* gA = vb + ((size_t)b * 256 + m0) * 256;
  const uint16_t* gB = w3t + (size_t)n0 * 256;

  floatx4 acc[4][5];
  #pragma unroll
  for (int i = 0; i < 4; ++i)
    #pragma unroll
    for (int j = 0; j < 5; ++j)
      acc[i][j] = (floatx4)0.0f;

  for (int ks = 0; ks < 256; ks += 32) {
    __syncthreads();
    #pragma unroll
    for (int q = 0; q < 2; ++q) {       // A: 8 KB
      const int fe = q * 2048 + t * 8;
      const int m = fe >> 5, k = fe & 31;
      gload_lds16(gA + (size_t)m * 256 + ks + k, (char*)as_ + fe * 2);
    }
    #pragma unroll
    for (int q = 0; q < 2; ++q) {       // B: first 8 KB
      const int fe = q * 2048 + t * 8;
      const int n = fe >> 5, k = fe & 31;
      gload_lds16(gB + (size_t)n * 256 + ks + k, (char*)bs_ + fe * 2);
    }
    if (t < 128) {                      // B: last 2 KB
      const int fe = 4096 + t * 8;
      const int n = fe >> 5, k = fe & 31;
      gload_lds16(gB + (size_t)n * 256 + ks + k, (char*)bs_ + fe * 2);
    }
    __syncthreads();

    short8 af[4], bf[5];
    #pragma unroll
    for (int am = 0; am < 4; ++am) {
      const int row = wm * 64 + am * 16 + lr;
      af[am] = *(const short8*)(as_ + row * 32 + lg * 8);
    }
    #pragma unroll
    for (int bn = 0; bn < 5; ++bn) {
      const int row = wn * 80 + bn * 16 + lr;
      bf[bn] = *(const short8*)(bs_ + row * 32 + lg * 8);
    }
    #pragma unroll
    for (int am = 0; am < 4; ++am)
      #pragma unroll
      for (int bn = 0; bn < 5; ++bn)
        acc[am][bn] = __builtin_amdgcn_mfma_f32_16x16x32_bf16(
            af[am], bf[bn], acc[am][bn], 0, 0, 0);
  }

  // epilogue: + bias, store bf16
  #pragma unroll
  for (int bn = 0; bn < 5; ++bn) {
    const int col = n0 + wn * 80 + bn * 16 + lr;
    const float bias = bl[3 + col];
    #pragma unroll
    for (int am = 0; am < 4; ++am) {
      #pragma unroll
      for (int rg = 0; rg < 4; ++rg) {
        const int row = m0 + wm * 64 + am * 16 + lg * 4 + rg;
        pw[((size_t)b * 256 + row) * NPW + col] = f2bf(acc[am][bn][rg] + bias);
      }
    }
  }
}

// ---------------- K2: out = LN(pw @ rT^T) * gamma + beta  (MFMA bf16) -------
// per batch: M=256, N=256 (channels), K=320. BM=64, BN=256, BK=32.
__global__ __launch_bounds__(256) void gemm2_kernel(
    const uint16_t* __restrict__ pw, const uint16_t* __restrict__ rT,
    const float* __restrict__ gamma, const float* __restrict__ beta,
    float* __restrict__ out)
{
  __shared__ uint16_t as_[64 * 32];    // 4 KB, [m][k]
  __shared__ uint16_t bs_[256 * 32];   // 16 KB, [c][k]
  __shared__ float reds[64][4], redq[64][4];
  __shared__ float muv[64], rsv[64];
  const int t  = threadIdx.x;
  const int b  = blockIdx.x >> 2;
  const int m0 = (blockIdx.x & 3) * 64;
  const int wid = t >> 6, lane = t & 63;
  const int lr = lane & 15, lg = lane >> 4;

  const uint16_t* gA = pw + ((size_t)b * 256 + m0) * NPW;
  const uint16_t* gB = rT + (size_t)b * 256 * NPW;

  floatx4 acc[4][4];
  #pragma unroll
  for (int i = 0; i < 4; ++i)
    #pragma unroll
    for (int j = 0; j < 4; ++j)
      acc[i][j] = (floatx4)0.0f;

  for (int ks = 0; ks < 320; ks += 32) {
    __syncthreads();
    {                                   // A: 4 KB
      const int fe = t * 8;
      const int m = fe >> 5, k = fe & 31;
      gload_lds16(gA + (size_t)m * NPW + ks + k, (char*)as_ + fe * 2);
    }
    #pragma unroll
    for (int q = 0; q < 4; ++q) {       // B: 16 KB
      const int fe = q * 2048 + t * 8;
      const int c = fe >> 5, k = fe & 31;
      gload_lds16(gB + (size_t)c * NPW + ks + k, (char*)bs_ + fe * 2);
    }
    __syncthreads();

    short8 af[4], bf[4];
    #pragma unroll
    for (int am = 0; am < 4; ++am) {
      const int row = am * 16 + lr;
      af[am] = *(const short8*)(as_ + row * 32 + lg * 8);
    }
    #pragma unroll
    for (int bn = 0; bn < 4; ++bn) {
      const int row = wid * 64 + bn * 16 + lr;
      bf[bn] = *(const short8*)(bs_ + row * 32 + lg * 8);
    }
    #pragma unroll
    for (int am = 0; am < 4; ++am)
      #pragma unroll
      for (int bn = 0; bn < 4; ++bn)
        acc[am][bn] = __builtin_amdgcn_mfma_f32_16x16x32_bf16(
            af[am], bf[bn], acc[am][bn], 0, 0, 0);
  }

  // ---- fused LayerNorm over 256 channels ----
  #pragma unroll
  for (int am = 0; am < 4; ++am) {
    #pragma unroll
    for (int rg = 0; rg < 4; ++rg) {
      float s = 0.f, q2 = 0.f;
      #pragma unroll
      for (int bn = 0; bn < 4; ++bn) {
        const float v = acc[am][bn][rg];
        s += v; q2 += v * v;
      }
      #pragma unroll
      for (int off = 1; off < 16; off <<= 1) {
        s  += __shfl_xor(s, off);
        q2 += __shfl_xor(q2, off);
      }
      if (lr == 0) {
        const int row = am * 16 + lg * 4 + rg;
        reds[row][wid] = s; redq[row][wid] = q2;
      }
    }
  }
  __syncthreads();
  if (t < 64) {
    const float S = reds[t][0] + reds[t][1] + reds[t][2] + reds[t][3];
    const float Q = redq[t][0] + redq[t][1] + redq[t][2] + redq[t][3];
    const float mu = S * (1.0f / 256.0f);
    const float var = Q * (1.0f / 256.0f) - mu * mu;
    muv[t] = mu;
    rsv[t] = rsqrtf(var + LN_EPS);
  }
  __syncthreads();

  #pragma unroll
  for (int bn = 0; bn < 4; ++bn) {
    const int col = wid * 64 + bn * 16 + lr;
    const float g = gamma[col], be = beta[col];
    #pragma unroll
    for (int am = 0; am < 4; ++am) {
      #pragma unroll
      for (int rg = 0; rg < 4; ++rg) {
        const int row = am * 16 + lg * 4 + rg;
        out[((size_t)b * 256 + m0 + row) * 256 + col] =
            (acc[am][bn][rg] - muv[row]) * rsv[row] * g + be;
      }
    }
  }
}

extern "C" void kernel_launch(void* const* d_in, const int* in_sizes, int n_in,
                              void* d_out, int out_size, void* d_ws, size_t ws_size,
                              hipStream_t stream) {
  const float* query = (const float*)d_in[0];
  const float* value = (const float*)d_in[1];
  const float* w     = (const float*)d_in[2];
  const float* bl    = (const float*)d_in[3];
  const float* gamma = (const float*)d_in[4];
  const float* beta  = (const float*)d_in[5];
  float* out = (float*)d_out;

  uint16_t* vb  = (uint16_t*)d_ws;                       // 256*256*256 bf16
  uint16_t* rT  = vb + (size_t)NB * 256 * 256;           // 256*256*320 bf16
  uint16_t* pw  = rT + (size_t)NB * 256 * NPW;           // 256*256*320 bf16
  uint16_t* w3t = pw + (size_t)NB * 256 * NPW;           // 320*256 bf16

  hipLaunchKernelGGL(wprep_kernel, dim3(NPW), dim3(256), 0, stream, w, w3t);
  hipLaunchKernelGGL(prep_kernel, dim3(NB * 10), dim3(256), 0, stream,
                     query, value, w, bl, vb, rT);
  hipLaunchKernelGGL(gemm1_kernel, dim3(NB * 4), dim3(256), 0, stream,
                     vb, w3t, bl, pw);
  hipLaunchKernelGGL(gemm2_kernel, dim3(NB * 4), dim3(256), 0, stream,
                     pw, rT, gamma, beta, out);
}

// Round 3
// 149.808 us; speedup vs baseline: 4.8388x; 1.0362x over previous
//
#include <hip/hip_runtime.h>
#include <cstddef>
#include <cstdint>

#define NB 256
#define CH 256
#define NTOK 320
#define NPW 320
#define NCOL 323
#define LN_EPS 1e-5f

typedef short short8 __attribute__((ext_vector_type(8)));
typedef float floatx4 __attribute__((ext_vector_type(4)));

__device__ __forceinline__ uint16_t f2bf(float f) {
  uint32_t u = __builtin_bit_cast(uint32_t, f);
  u += 0x7FFFu + ((u >> 16) & 1u);          // round-to-nearest-even
  return (uint16_t)(u >> 16);
}

__device__ __forceinline__ void gload_lds16(const void* g, void* l) {
  __builtin_amdgcn_global_load_lds(
      (const __attribute__((address_space(1))) unsigned int*)g,
      (__attribute__((address_space(3))) unsigned int*)l, 16, 0, 0);
}

// ---------------- K00: w3t[n][k] = bf16(w[k][3+n]); w012[tap][k] ------------
__global__ __launch_bounds__(256) void wprep_kernel(
    const float* __restrict__ w, uint16_t* __restrict__ w3t,
    float* __restrict__ w012) {
  const int n = blockIdx.x;     // 0..322
  const int k = threadIdx.x;    // 0..255
  if (n < NPW) w3t[n * 256 + k] = f2bf(w[k * NCOL + 3 + n]);
  else         w012[(n - NPW) * 256 + k] = w[k * NCOL + (n - NPW)];
}

// ---------------- K0: dw + conv -> rT (bf16, transposed), vb = bf16(value) --
// 8 token rows per block, 256 threads, grid = NB * 40.
__global__ __launch_bounds__(256) void prep_kernel(
    const float* __restrict__ query, const float* __restrict__ value,
    const float* __restrict__ w012, const float* __restrict__ bl,
    uint16_t* __restrict__ vb, uint16_t* __restrict__ rT)
{
  __shared__ float xs[8][256];      // 8 KB
  __shared__ float w3s[3][256];     // 3 KB
  __shared__ float dwv[8][3];
  const int t  = threadIdx.x;
  const int b  = blockIdx.x / 40;
  const int n0 = (blockIdx.x % 40) * 8;
  const bool isval = (n0 < 256);
  const float* src = isval ? (value + ((size_t)b * 256 + n0) * CH)
                           : (query + ((size_t)b * 64 + (n0 - 256)) * CH);
  // stage 8 rows; keep in registers; optionally emit vb (bf16 value copy)
  float4 xv[2];
  #pragma unroll
  for (int q = 0; q < 2; ++q) {
    const int fe = q * 1024 + t * 4;
    xv[q] = *(const float4*)(src + fe);
    *(float4*)&xs[fe >> 8][fe & 255] = xv[q];
    if (isval) {
      ushort4 h;
      h.x = f2bf(xv[q].x); h.y = f2bf(xv[q].y);
      h.z = f2bf(xv[q].z); h.w = f2bf(xv[q].w);
      *(ushort4*)(vb + ((size_t)b * 256 + n0) * CH + fe) = h;
    }
  }
  ((float*)w3s)[t]       = w012[t];
  ((float*)w3s)[t + 256] = w012[t + 256];
  ((float*)w3s)[t + 512] = w012[t + 512];
  __syncthreads();

  // dw: wave wid holds rows {wid, 4+wid} in registers (cols 4*lane..4*lane+3)
  const int wid = t >> 6, lane = t & 63;
  const float4 w0 = *(const float4*)&w3s[0][lane * 4];
  const float4 w1 = *(const float4*)&w3s[1][lane * 4];
  const float4 w2 = *(const float4*)&w3s[2][lane * 4];
  #pragma unroll
  for (int q = 0; q < 2; ++q) {
    const int row = q * 4 + wid;
    float p0 = xv[q].x * w0.x, p1 = xv[q].x * w1.x, p2 = xv[q].x * w2.x;
    p0 = fmaf(xv[q].y, w0.y, p0); p1 = fmaf(xv[q].y, w1.y, p1); p2 = fmaf(xv[q].y, w2.y, p2);
    p0 = fmaf(xv[q].z, w0.z, p0); p1 = fmaf(xv[q].z, w1.z, p1); p2 = fmaf(xv[q].z, w2.z, p2);
    p0 = fmaf(xv[q].w, w0.w, p0); p1 = fmaf(xv[q].w, w1.w, p1); p2 = fmaf(xv[q].w, w2.w, p2);
    #pragma unroll
    for (int off = 32; off; off >>= 1) {
      p0 += __shfl_xor(p0, off);
      p1 += __shfl_xor(p1, off);
      p2 += __shfl_xor(p2, off);
    }
    if (lane == 0) {
      dwv[row][0] = p0 + bl[0];
      dwv[row][1] = p1 + bl[1];
      dwv[row][2] = p2 + bl[2];
    }
  }
  __syncthreads();

  // conv (3-tap over channels, zero pad) + ReLU -> one uint4 per thread
  uint16_t hbuf[8];
  #pragma unroll
  for (int i = 0; i < 8; ++i) {
    const float xm = (t > 0)   ? xs[i][t - 1] : 0.0f;
    const float xc = xs[i][t];
    const float xp = (t < 255) ? xs[i][t + 1] : 0.0f;
    float v = fmaf(dwv[i][0], xm, fmaf(dwv[i][1], xc, dwv[i][2] * xp));
    v = fmaxf(v, 0.0f);
    hbuf[i] = f2bf(v);
  }
  *(uint4*)(rT + ((size_t)b * 256 + t) * NPW + n0) = *(uint4*)hbuf;
}

// ---------------- K1: pw = vb @ w3t^T + bias  (MFMA bf16) ----------------
// per batch: M=256 (value tokens), N=320 (pw cols), K=256. BM=128, BN=160, BK=32.
__global__ __launch_bounds__(256) void gemm1_kernel(
    const uint16_t* __restrict__ vb, const uint16_t* __restrict__ w3t,
    const float* __restrict__ bl, uint16_t* __restrict__ pw)
{
  __shared__ uint16_t as_[128 * 32];   // 8 KB, [m][k] row-major
  __shared__ uint16_t bs_[160 * 32];   // 10 KB, [n][k] row-major
  const int t   = threadIdx.x;
  const int bid = blockIdx.x;
  const int b   = bid >> 2;
  const int m0  = ((bid >> 1) & 1) * 128;
  const int n0  = (bid & 1) * 160;
  const int wid = t >> 6, lane = t & 63;
  const int wm = wid >> 1, wn = wid & 1;
  const int lr = lane & 15, lg = lane >> 4;

  const uint16_t* gA = vb + ((size_t)b * 256 + m0) * 256;
  const uint16_t* gB = w3t + (size_t)n0 * 256;

  floatx4 acc[4][5];
  #pragma unroll
  for (int i = 0; i < 4; ++i)
    #pragma unroll
    for (int j = 0; j < 5; ++j)
      acc[i][j] = (floatx4)0.0f;

  for (int ks = 0; ks < 256; ks += 32) {
    __syncthreads();
    #pragma unroll
    for (int q = 0; q < 2; ++q) {       // A: 8 KB
      const int fe = q * 2048 + t * 8;
      const int m = fe >> 5, k = fe & 31;
      gload_lds16(gA + (size_t)m * 256 + ks + k, (char*)as_ + fe * 2);
    }
    #pragma unroll
    for (int q = 0; q < 2; ++q) {       // B: first 8 KB
      const int fe = q * 2048 + t * 8;
      const int n = fe >> 5, k = fe & 31;
      gload_lds16(gB + (size_t)n * 256 + ks + k, (char*)bs_ + fe * 2);
    }
    if (t < 128) {                      // B: last 2 KB
      const int fe = 4096 + t * 8;
      const int n = fe >> 5, k = fe & 31;
      gload_lds16(gB + (size_t)n * 256 + ks + k, (char*)bs_ + fe * 2);
    }
    __syncthreads();

    short8 af[4], bf[5];
    #pragma unroll
    for (int am = 0; am < 4; ++am) {
      const int row = wm * 64 + am * 16 + lr;
      af[am] = *(const short8*)(as_ + row * 32 + lg * 8);
    }
    #pragma unroll
    for (int bn = 0; bn < 5; ++bn) {
      const int row = wn * 80 + bn * 16 + lr;
      bf[bn] = *(const short8*)(bs_ + row * 32 + lg * 8);
    }
    #pragma unroll
    for (int am = 0; am < 4; ++am)
      #pragma unroll
      for (int bn = 0; bn < 5; ++bn)
        acc[am][bn] = __builtin_amdgcn_mfma_f32_16x16x32_bf16(
            af[am], bf[bn], acc[am][bn], 0, 0, 0);
  }

  // epilogue: + bias, store bf16
  #pragma unroll
  for (int bn = 0; bn < 5; ++bn) {
    const int col = n0 + wn * 80 + bn * 16 + lr;
    const float bias = bl[3 + col];
    #pragma unroll
    for (int am = 0; am < 4; ++am) {
      #pragma unroll
      for (int rg = 0; rg < 4; ++rg) {
        const int row = m0 + wm * 64 + am * 16 + lg * 4 + rg;
        pw[((size_t)b * 256 + row) * NPW + col] = f2bf(acc[am][bn][rg] + bias);
      }
    }
  }
}

// ---------------- K2: out = LN(pw @ rT^T) * gamma + beta  (MFMA bf16) -------
// per batch: M=256, N=256 (channels), K=320. BM=64, BN=256, BK=32.
__global__ __launch_bounds__(256) void gemm2_kernel(
    const uint16_t* __restrict__ pw, const uint16_t* __restrict__ rT,
    const float* __restrict__ gamma, const float* __restrict__ beta,
    float* __restrict__ out)
{
  __shared__ uint16_t as_[64 * 32];    // 4 KB, [m][k]
  __shared__ uint16_t bs_[256 * 32];   // 16 KB, [c][k]
  __shared__ float reds[64][4], redq[64][4];
  __shared__ float muv[64], rsv[64];
  const int t  = threadIdx.x;
  const int b  = blockIdx.x >> 2;
  const int m0 = (blockIdx.x & 3) * 64;
  const int wid = t >> 6, lane = t & 63;
  const int lr = lane & 15, lg = lane >> 4;

  const uint16_t* gA = pw + ((size_t)b * 256 + m0) * NPW;
  const uint16_t* gB = rT + (size_t)b * 256 * NPW;

  floatx4 acc[4][4];
  #pragma unroll
  for (int i = 0; i < 4; ++i)
    #pragma unroll
    for (int j = 0; j < 4; ++j)
      acc[i][j] = (floatx4)0.0f;

  for (int ks = 0; ks < 320; ks += 32) {
    __syncthreads();
    {                                   // A: 4 KB
      const int fe = t * 8;
      const int m = fe >> 5, k = fe & 31;
      gload_lds16(gA + (size_t)m * NPW + ks + k, (char*)as_ + fe * 2);
    }
    #pragma unroll
    for (int q = 0; q < 4; ++q) {       // B: 16 KB
      const int fe = q * 2048 + t * 8;
      const int c = fe >> 5, k = fe & 31;
      gload_lds16(gB + (size_t)c * NPW + ks + k, (char*)bs_ + fe * 2);
    }
    __syncthreads();

    short8 af[4], bf[4];
    #pragma unroll
    for (int am = 0; am < 4; ++am) {
      const int row = am * 16 + lr;
      af[am] = *(const short8*)(as_ + row * 32 + lg * 8);
    }
    #pragma unroll
    for (int bn = 0; bn < 4; ++bn) {
      const int row = wid * 64 + bn * 16 + lr;
      bf[bn] = *(const short8*)(bs_ + row * 32 + lg * 8);
    }
    #pragma unroll
    for (int am = 0; am < 4; ++am)
      #pragma unroll
      for (int bn = 0; bn < 4; ++bn)
        acc[am][bn] = __builtin_amdgcn_mfma_f32_16x16x32_bf16(
            af[am], bf[bn], acc[am][bn], 0, 0, 0);
  }

  // ---- fused LayerNorm over 256 channels ----
  #pragma unroll
  for (int am = 0; am < 4; ++am) {
    #pragma unroll
    for (int rg = 0; rg < 4; ++rg) {
      float s = 0.f, q2 = 0.f;
      #pragma unroll
      for (int bn = 0; bn < 4; ++bn) {
        const float v = acc[am][bn][rg];
        s += v; q2 += v * v;
      }
      #pragma unroll
      for (int off = 1; off < 16; off <<= 1) {
        s  += __shfl_xor(s, off);
        q2 += __shfl_xor(q2, off);
      }
      if (lr == 0) {
        const int row = am * 16 + lg * 4 + rg;
        reds[row][wid] = s; redq[row][wid] = q2;
      }
    }
  }
  __syncthreads();
  if (t < 64) {
    const float S = reds[t][0] + reds[t][1] + reds[t][2] + reds[t][3];
    const float Q = redq[t][0] + redq[t][1] + redq[t][2] + redq[t][3];
    const float mu = S * (1.0f / 256.0f);
    const float var = Q * (1.0f / 256.0f) - mu * mu;
    muv[t] = mu;
    rsv[t] = rsqrtf(var + LN_EPS);
  }
  __syncthreads();

  #pragma unroll
  for (int bn = 0; bn < 4; ++bn) {
    const int col = wid * 64 + bn * 16 + lr;
    const float g = gamma[col], be = beta[col];
    #pragma unroll
    for (int am = 0; am < 4; ++am) {
      #pragma unroll
      for (int rg = 0; rg < 4; ++rg) {
        const int row = am * 16 + lg * 4 + rg;
        out[((size_t)b * 256 + m0 + row) * 256 + col] =
            (acc[am][bn][rg] - muv[row]) * rsv[row] * g + be;
      }
    }
  }
}

extern "C" void kernel_launch(void* const* d_in, const int* in_sizes, int n_in,
                              void* d_out, int out_size, void* d_ws, size_t ws_size,
                              hipStream_t stream) {
  const float* query = (const float*)d_in[0];
  const float* value = (const float*)d_in[1];
  const float* w     = (const float*)d_in[2];
  const float* bl    = (const float*)d_in[3];
  const float* gamma = (const float*)d_in[4];
  const float* beta  = (const float*)d_in[5];
  float* out = (float*)d_out;

  uint16_t* vb   = (uint16_t*)d_ws;                      // 256*256*256 bf16
  uint16_t* rT   = vb + (size_t)NB * 256 * 256;          // 256*256*320 bf16
  uint16_t* pw   = rT + (size_t)NB * 256 * NPW;          // 256*256*320 bf16
  uint16_t* w3t  = pw + (size_t)NB * 256 * NPW;          // 320*256 bf16
  float*    w012 = (float*)(w3t + (size_t)NPW * 256);    // 3*256 fp32

  hipLaunchKernelGGL(wprep_kernel, dim3(NCOL), dim3(256), 0, stream, w, w3t, w012);
  hipLaunchKernelGGL(prep_kernel, dim3(NB * 40), dim3(256), 0, stream,
                     query, value, w012, bl, vb, rT);
  hipLaunchKernelGGL(gemm1_kernel, dim3(NB * 4), dim3(256), 0, stream,
                     vb, w3t, bl, pw);
  hipLaunchKernelGGL(gemm2_kernel, dim3(NB * 4), dim3(256), 0, stream,
                     pw, rT, gamma, beta, out);
}

// Round 4
// 142.869 us; speedup vs baseline: 5.0738x; 1.0486x over previous
//
#include <hip/hip_runtime.h>
#include <cstddef>
#include <cstdint>

#define NB 256
#define CH 256
#define NTOK 320
#define NPW 320
#define NCOL 323
#define LN_EPS 1e-5f

typedef short short8 __attribute__((ext_vector_type(8)));
typedef float floatx4 __attribute__((ext_vector_type(4)));

__device__ __forceinline__ uint16_t f2bf(float f) {
  uint32_t u = __builtin_bit_cast(uint32_t, f);
  u += 0x7FFFu + ((u >> 16) & 1u);          // round-to-nearest-even
  return (uint16_t)(u >> 16);
}

__device__ __forceinline__ void gload_lds16(const void* g, void* l) {
  __builtin_amdgcn_global_load_lds(
      (const __attribute__((address_space(1))) unsigned int*)g,
      (__attribute__((address_space(3))) unsigned int*)l, 16, 0, 0);
}

// ---------------- K00: w3t[n][k] = bf16(w[k][3+n]); w012[tap][k] ------------
__global__ __launch_bounds__(256) void wprep_kernel(
    const float* __restrict__ w, uint16_t* __restrict__ w3t,
    float* __restrict__ w012) {
  const int n = blockIdx.x;     // 0..322
  const int k = threadIdx.x;    // 0..255
  if (n < NPW) w3t[n * 256 + k] = f2bf(w[k * NCOL + 3 + n]);
  else         w012[(n - NPW) * 256 + k] = w[k * NCOL + (n - NPW)];
}

// ---------------- K0: dw + conv -> rT (bf16, transposed), vb = bf16(value) --
__global__ __launch_bounds__(256) void prep_kernel(
    const float* __restrict__ query, const float* __restrict__ value,
    const float* __restrict__ w012, const float* __restrict__ bl,
    uint16_t* __restrict__ vb, uint16_t* __restrict__ rT)
{
  __shared__ float xs[8][256];      // 8 KB
  __shared__ float w3s[3][256];     // 3 KB
  __shared__ float dwv[8][3];
  const int t  = threadIdx.x;
  const int b  = blockIdx.x / 40;
  const int n0 = (blockIdx.x % 40) * 8;
  const bool isval = (n0 < 256);
  const float* src = isval ? (value + ((size_t)b * 256 + n0) * CH)
                           : (query + ((size_t)b * 64 + (n0 - 256)) * CH);
  float4 xv[2];
  #pragma unroll
  for (int q = 0; q < 2; ++q) {
    const int fe = q * 1024 + t * 4;
    xv[q] = *(const float4*)(src + fe);
    *(float4*)&xs[fe >> 8][fe & 255] = xv[q];
    if (isval) {
      ushort4 h;
      h.x = f2bf(xv[q].x); h.y = f2bf(xv[q].y);
      h.z = f2bf(xv[q].z); h.w = f2bf(xv[q].w);
      *(ushort4*)(vb + ((size_t)b * 256 + n0) * CH + fe) = h;
    }
  }
  ((float*)w3s)[t]       = w012[t];
  ((float*)w3s)[t + 256] = w012[t + 256];
  ((float*)w3s)[t + 512] = w012[t + 512];
  __syncthreads();

  const int wid = t >> 6, lane = t & 63;
  const float4 w0 = *(const float4*)&w3s[0][lane * 4];
  const float4 w1 = *(const float4*)&w3s[1][lane * 4];
  const float4 w2 = *(const float4*)&w3s[2][lane * 4];
  #pragma unroll
  for (int q = 0; q < 2; ++q) {
    const int row = q * 4 + wid;
    float p0 = xv[q].x * w0.x, p1 = xv[q].x * w1.x, p2 = xv[q].x * w2.x;
    p0 = fmaf(xv[q].y, w0.y, p0); p1 = fmaf(xv[q].y, w1.y, p1); p2 = fmaf(xv[q].y, w2.y, p2);
    p0 = fmaf(xv[q].z, w0.z, p0); p1 = fmaf(xv[q].z, w1.z, p1); p2 = fmaf(xv[q].z, w2.z, p2);
    p0 = fmaf(xv[q].w, w0.w, p0); p1 = fmaf(xv[q].w, w1.w, p1); p2 = fmaf(xv[q].w, w2.w, p2);
    #pragma unroll
    for (int off = 32; off; off >>= 1) {
      p0 += __shfl_xor(p0, off);
      p1 += __shfl_xor(p1, off);
      p2 += __shfl_xor(p2, off);
    }
    if (lane == 0) {
      dwv[row][0] = p0 + bl[0];
      dwv[row][1] = p1 + bl[1];
      dwv[row][2] = p2 + bl[2];
    }
  }
  __syncthreads();

  uint16_t hbuf[8];
  #pragma unroll
  for (int i = 0; i < 8; ++i) {
    const float xm = (t > 0)   ? xs[i][t - 1] : 0.0f;
    const float xc = xs[i][t];
    const float xp = (t < 255) ? xs[i][t + 1] : 0.0f;
    float v = fmaf(dwv[i][0], xm, fmaf(dwv[i][1], xc, dwv[i][2] * xp));
    v = fmaxf(v, 0.0f);
    hbuf[i] = f2bf(v);
  }
  *(uint4*)(rT + ((size_t)b * 256 + t) * NPW + n0) = *(uint4*)hbuf;
}

// ---------------- K1: pw = vb @ w3t^T + bias  (MFMA bf16, dbuf) -------------
// M=256, N=320, K=256 per batch. BM=128, BN=160, BK=32, 4 waves (2M x 2N).
// LDS layout: kgroup-major [k/8][row][8 elems] (conflict-free b128 reads).
__global__ __launch_bounds__(256) void gemm1_kernel(
    const uint16_t* __restrict__ vb, const uint16_t* __restrict__ w3t,
    const float* __restrict__ bl, uint16_t* __restrict__ pw)
{
  __shared__ uint16_t as_[2][4096];    // 2 x 8 KB  (512 slots of 16B)
  __shared__ uint16_t bs_[2][5120];    // 2 x 10 KB (640 slots of 16B)
  const int t   = threadIdx.x;
  const int tid = ((blockIdx.x & 7) << 7) + (blockIdx.x >> 3);  // XCD swizzle
  const int b   = tid >> 2;
  const int m0  = ((tid >> 1) & 1) * 128;
  const int n0  = (tid & 1) * 160;
  const int wid = t >> 6, lane = t & 63;
  const int wm = wid >> 1, wn = wid & 1;
  const int lr = lane & 15, lg = lane >> 4;

  const uint16_t* gA = vb + ((size_t)b * 256 + m0) * 256;
  const uint16_t* gB = w3t + (size_t)n0 * 256;

  floatx4 acc[4][5];
  #pragma unroll
  for (int i = 0; i < 4; ++i)
    #pragma unroll
    for (int j = 0; j < 5; ++j)
      acc[i][j] = (floatx4)0.0f;

#define STAGE1(buf, ks)                                                        \
  {                                                                            \
    _Pragma("unroll")                                                          \
    for (int q = 0; q < 2; ++q) {                                              \
      const int s = q * 256 + t;                                               \
      const int g = s >> 7, r = s & 127;                                       \
      gload_lds16(gA + (size_t)r * 256 + (ks) + g * 8,                         \
                  (char*)as_[buf] + s * 16);                                   \
    }                                                                          \
    _Pragma("unroll")                                                          \
    for (int q = 0; q < 2; ++q) {                                              \
      const int s = q * 256 + t;                                               \
      const int g = s / 160, r = s - g * 160;                                  \
      gload_lds16(gB + (size_t)r * 256 + (ks) + g * 8,                         \
                  (char*)bs_[buf] + s * 16);                                   \
    }                                                                          \
    if (t < 128) {                                                             \
      const int s = 512 + t;                                                   \
      const int g = s / 160, r = s - g * 160;                                  \
      gload_lds16(gB + (size_t)r * 256 + (ks) + g * 8,                         \
                  (char*)bs_[buf] + s * 16);                                   \
    }                                                                          \
  }

  STAGE1(0, 0);
  for (int kt = 0; kt < 8; ++kt) {
    const int cur = kt & 1;
    __syncthreads();                       // stage(kt) done; prev reads done
    if (kt < 7) STAGE1(cur ^ 1, (kt + 1) * 32);

    short8 af[4], bf[5];
    #pragma unroll
    for (int am = 0; am < 4; ++am) {
      const int row = wm * 64 + am * 16 + lr;
      af[am] = *(const short8*)(as_[cur] + (lg * 128 + row) * 8);
    }
    #pragma unroll
    for (int bn = 0; bn < 5; ++bn) {
      const int row = wn * 80 + bn * 16 + lr;
      bf[bn] = *(const short8*)(bs_[cur] + (lg * 160 + row) * 8);
    }
    #pragma unroll
    for (int am = 0; am < 4; ++am)
      #pragma unroll
      for (int bn = 0; bn < 5; ++bn)
        acc[am][bn] = __builtin_amdgcn_mfma_f32_16x16x32_bf16(
            af[am], bf[bn], acc[am][bn], 0, 0, 0);
  }
#undef STAGE1

  #pragma unroll
  for (int bn = 0; bn < 5; ++bn) {
    const int col = n0 + wn * 80 + bn * 16 + lr;
    const float bias = bl[3 + col];
    #pragma unroll
    for (int am = 0; am < 4; ++am) {
      #pragma unroll
      for (int rg = 0; rg < 4; ++rg) {
        const int row = m0 + wm * 64 + am * 16 + lg * 4 + rg;
        pw[((size_t)b * 256 + row) * NPW + col] = f2bf(acc[am][bn][rg] + bias);
      }
    }
  }
}

// ---------------- K2: out = LN(pw @ rT^T) * gamma + beta  (MFMA bf16, dbuf) -
// M=256, N=256, K=320 per batch. BM=64, BN=256, BK=32, 4 waves (1M x 4N).
__global__ __launch_bounds__(256) void gemm2_kernel(
    const uint16_t* __restrict__ pw, const uint16_t* __restrict__ rT,
    const float* __restrict__ gamma, const float* __restrict__ beta,
    float* __restrict__ out)
{
  __shared__ uint16_t as_[2][2048];    // 2 x 4 KB  (256 slots)
  __shared__ uint16_t bs_[2][8192];    // 2 x 16 KB (1024 slots)
  __shared__ float reds[64][4], redq[64][4];
  __shared__ float muv[64], rsv[64];
  const int t   = threadIdx.x;
  const int tid = ((blockIdx.x & 7) << 7) + (blockIdx.x >> 3);  // XCD swizzle
  const int b   = tid >> 2;
  const int m0  = (tid & 3) * 64;
  const int wid = t >> 6, lane = t & 63;
  const int lr = lane & 15, lg = lane >> 4;

  const uint16_t* gA = pw + ((size_t)b * 256 + m0) * NPW;
  const uint16_t* gB = rT + (size_t)b * 256 * NPW;

  floatx4 acc[4][4];
  #pragma unroll
  for (int i = 0; i < 4; ++i)
    #pragma unroll
    for (int j = 0; j < 4; ++j)
      acc[i][j] = (floatx4)0.0f;

#define STAGE2(buf, ks)                                                        \
  {                                                                            \
    {                                                                          \
      const int s = t;                                                         \
      const int g = s >> 6, r = s & 63;                                        \
      gload_lds16(gA + (size_t)r * NPW + (ks) + g * 8,                         \
                  (char*)as_[buf] + s * 16);                                   \
    }                                                                          \
    _Pragma("unroll")                                                          \
    for (int q = 0; q < 4; ++q) {                                              \
      const int s = q * 256 + t;                                               \
      const int g = s >> 8, r = s & 255;                                       \
      gload_lds16(gB + (size_t)r * NPW + (ks) + g * 8,                         \
                  (char*)bs_[buf] + s * 16);                                   \
    }                                                                          \
  }

  STAGE2(0, 0);
  for (int kt = 0; kt < 10; ++kt) {
    const int cur = kt & 1;
    __syncthreads();
    if (kt < 9) STAGE2(cur ^ 1, (kt + 1) * 32);

    short8 af[4], bf[4];
    #pragma unroll
    for (int am = 0; am < 4; ++am) {
      const int row = am * 16 + lr;
      af[am] = *(const short8*)(as_[cur] + (lg * 64 + row) * 8);
    }
    #pragma unroll
    for (int bn = 0; bn < 4; ++bn) {
      const int row = wid * 64 + bn * 16 + lr;
      bf[bn] = *(const short8*)(bs_[cur] + (lg * 256 + row) * 8);
    }
    #pragma unroll
    for (int am = 0; am < 4; ++am)
      #pragma unroll
      for (int bn = 0; bn < 4; ++bn)
        acc[am][bn] = __builtin_amdgcn_mfma_f32_16x16x32_bf16(
            af[am], bf[bn], acc[am][bn], 0, 0, 0);
  }
#undef STAGE2

  // ---- fused LayerNorm over 256 channels ----
  #pragma unroll
  for (int am = 0; am < 4; ++am) {
    #pragma unroll
    for (int rg = 0; rg < 4; ++rg) {
      float s = 0.f, q2 = 0.f;
      #pragma unroll
      for (int bn = 0; bn < 4; ++bn) {
        const float v = acc[am][bn][rg];
        s += v; q2 += v * v;
      }
      #pragma unroll
      for (int off = 1; off < 16; off <<= 1) {
        s  += __shfl_xor(s, off);
        q2 += __shfl_xor(q2, off);
      }
      if (lr == 0) {
        const int row = am * 16 + lg * 4 + rg;
        reds[row][wid] = s; redq[row][wid] = q2;
      }
    }
  }
  __syncthreads();
  if (t < 64) {
    const float S = reds[t][0] + reds[t][1] + reds[t][2] + reds[t][3];
    const float Q = redq[t][0] + redq[t][1] + redq[t][2] + redq[t][3];
    const float mu = S * (1.0f / 256.0f);
    const float var = Q * (1.0f / 256.0f) - mu * mu;
    muv[t] = mu;
    rsv[t] = rsqrtf(var + LN_EPS);
  }
  __syncthreads();

  #pragma unroll
  for (int bn = 0; bn < 4; ++bn) {
    const int col = wid * 64 + bn * 16 + lr;
    const float g = gamma[col], be = beta[col];
    #pragma unroll
    for (int am = 0; am < 4; ++am) {
      #pragma unroll
      for (int rg = 0; rg < 4; ++rg) {
        const int row = am * 16 + lg * 4 + rg;
        out[((size_t)b * 256 + m0 + row) * 256 + col] =
            (acc[am][bn][rg] - muv[row]) * rsv[row] * g + be;
      }
    }
  }
}

extern "C" void kernel_launch(void* const* d_in, const int* in_sizes, int n_in,
                              void* d_out, int out_size, void* d_ws, size_t ws_size,
                              hipStream_t stream) {
  const float* query = (const float*)d_in[0];
  const float* value = (const float*)d_in[1];
  const float* w     = (const float*)d_in[2];
  const float* bl    = (const float*)d_in[3];
  const float* gamma = (const float*)d_in[4];
  const float* beta  = (const float*)d_in[5];
  float* out = (float*)d_out;

  uint16_t* vb   = (uint16_t*)d_ws;                      // 256*256*256 bf16
  uint16_t* rT   = vb + (size_t)NB * 256 * 256;          // 256*256*320 bf16
  uint16_t* pw   = rT + (size_t)NB * 256 * NPW;          // 256*256*320 bf16
  uint16_t* w3t  = pw + (size_t)NB * 256 * NPW;          // 320*256 bf16
  float*    w012 = (float*)(w3t + (size_t)NPW * 256);    // 3*256 fp32

  hipLaunchKernelGGL(wprep_kernel, dim3(NCOL), dim3(256), 0, stream, w, w3t, w012);
  hipLaunchKernelGGL(prep_kernel, dim3(NB * 40), dim3(256), 0, stream,
                     query, value, w012, bl, vb, rT);
  hipLaunchKernelGGL(gemm1_kernel, dim3(NB * 4), dim3(256), 0, stream,
                     vb, w3t, bl, pw);
  hipLaunchKernelGGL(gemm2_kernel, dim3(NB * 4), dim3(256), 0, stream,
                     pw, rT, gamma, beta, out);
}